// Round 1
// baseline (77.762 us; speedup 1.0000x reference)
//
#include <hip/hip_runtime.h>

#define B   16
#define C1  256          // channels per input
#define C2  512          // total channels after concat
#define HW  4096         // 64*64 pixels per channel
#define TAIL_PER_B 4     // tail blocks per batch (each covers 1024 pixels)

// ---------------------------------------------------------------------------
// Kernel 1: per-(batch, channel) global sum over H*W  -> pooled[B*C2]
// (sum instead of mean: /4096 is exact, ordering identical)
// ---------------------------------------------------------------------------
__global__ __launch_bounds__(256) void pool_kernel(
    const float* __restrict__ x1, const float* __restrict__ x2,
    float* __restrict__ pooled)
{
    int bc = blockIdx.x;            // 0 .. B*C2-1
    int b  = bc >> 9;               // /512
    int c  = bc & (C2 - 1);
    const float* base = (c < C1)
        ? (x1 + (size_t)(b * C1 + c) * HW)
        : (x2 + (size_t)(b * C1 + (c - C1)) * HW);

    int t = threadIdx.x;            // 256 threads
    const float4* p = (const float4*)base;   // 1024 float4s per channel
    float s = 0.f;
    #pragma unroll
    for (int i = 0; i < 4; ++i) {
        float4 v = p[t + i * 256];
        s += v.x + v.y + v.z + v.w;
    }
    // wave-64 reduction
    #pragma unroll
    for (int off = 32; off > 0; off >>= 1)
        s += __shfl_down(s, off, 64);

    __shared__ float ws[4];
    int lane = t & 63, wid = t >> 6;
    if (lane == 0) ws[wid] = s;
    __syncthreads();
    if (t == 0)
        pooled[bc] = ws[0] + ws[1] + ws[2] + ws[3];
}

// ---------------------------------------------------------------------------
// Kernel 2: per-batch stable descending rank-sort of pooled values.
// idx[b*C2 + rank] = channel  (rank formula matches argsort(-pooled) stability)
// ---------------------------------------------------------------------------
__global__ __launch_bounds__(512) void sort_kernel(
    const float* __restrict__ pooled, int* __restrict__ idx)
{
    int b = blockIdx.x;
    int t = threadIdx.x;            // 512 threads = one per channel
    __shared__ float sp[C2];
    float v = pooled[b * C2 + t];
    sp[t] = v;
    __syncthreads();
    int rank = 0;
    for (int j = 0; j < C2; ++j) {
        float u = sp[j];
        rank += (u > v) || (u == v && j < t);
    }
    idx[b * C2 + rank] = t;
}

// ---------------------------------------------------------------------------
// Kernel 3: gather channels in sorted order; fold tail sum into channel k-1.
// Grid: [0, B*TAIL_PER_B)            -> tail blocks (channel k-1 + tail sum)
//       [B*TAIL_PER_B, +B*(k-1))     -> plain copy blocks (channels 0..k-2)
// ---------------------------------------------------------------------------
__global__ __launch_bounds__(256) void gather_kernel(
    const float* __restrict__ x1, const float* __restrict__ x2,
    const int* __restrict__ idx, float* __restrict__ out, int k)
{
    int t   = threadIdx.x;
    int bid = blockIdx.x;
    int ntail = B * TAIL_PER_B;
    __shared__ int ch[C2];          // worst-case tail channel list

    if (bid < ntail) {
        // ---- tail block: out[b, k-1, pix] = sum over channels idx[k-1..C2-1]
        int b     = bid / TAIL_PER_B;
        int chunk = bid % TAIL_PER_B;          // 1024 pixels per chunk
        int p4    = chunk * 256 + t;           // float4 index in channel (0..1023)
        int ntc   = C2 - k + 1;                // 257 channels to accumulate
        for (int i = t; i < ntc; i += 256)
            ch[i] = idx[b * C2 + (k - 1) + i];
        __syncthreads();

        float4 acc = make_float4(0.f, 0.f, 0.f, 0.f);
        for (int i = 0; i < ntc; ++i) {
            int c = ch[i];
            const float4* base = (const float4*)((c < C1)
                ? (x1 + (size_t)(b * C1 + c) * HW)
                : (x2 + (size_t)(b * C1 + (c - C1)) * HW));
            float4 v = base[p4];
            acc.x += v.x; acc.y += v.y; acc.z += v.z; acc.w += v.w;
        }
        float4* o = (float4*)(out + (size_t)(b * k + (k - 1)) * HW);
        o[p4] = acc;
    } else {
        // ---- plain copy block: out[b, o, :] = x[b, idx[b,o], :]
        int cb = bid - ntail;                  // 0 .. B*(k-1)-1
        int b  = cb / (k - 1);
        int o  = cb % (k - 1);
        int c  = idx[b * C2 + o];
        const float4* src = (const float4*)((c < C1)
            ? (x1 + (size_t)(b * C1 + c) * HW)
            : (x2 + (size_t)(b * C1 + (c - C1)) * HW));
        float4* dst = (float4*)(out + (size_t)(b * k + o) * HW);
        #pragma unroll
        for (int i = 0; i < 4; ++i)
            dst[t + i * 256] = src[t + i * 256];
    }
}

// ---------------------------------------------------------------------------
extern "C" void kernel_launch(void* const* d_in, const int* in_sizes, int n_in,
                              void* d_out, int out_size, void* d_ws, size_t ws_size,
                              hipStream_t stream)
{
    const float* x1 = (const float*)d_in[0];
    const float* x2 = (const float*)d_in[1];
    float* out = (float*)d_out;

    // k recovered from output size (deterministic, no device readback)
    int k = out_size / (B * HW);               // = 256

    float* pooled = (float*)d_ws;              // B*C2 floats = 32 KB
    int*   idx    = (int*)((char*)d_ws + B * C2 * sizeof(float)); // 32 KB

    pool_kernel<<<B * C2, 256, 0, stream>>>(x1, x2, pooled);
    sort_kernel<<<B, 512, 0, stream>>>(pooled, idx);

    int ngather = B * TAIL_PER_B + B * (k - 1);
    gather_kernel<<<ngather, 256, 0, stream>>>(x1, x2, idx, out, k);
}